// Round 8
// baseline (343.112 us; speedup 1.0000x reference)
//
#include <hip/hip_runtime.h>
#include <hip/hip_bf16.h>

typedef __attribute__((ext_vector_type(8))) short s16x8;
typedef __attribute__((ext_vector_type(4))) short s16x4;
typedef __attribute__((ext_vector_type(4))) float f32x4;

#define B_ 2
#define L_ 2048
#define E_ 2048
#define H_ 16
#define D_ 128

__device__ __forceinline__ float b2f(short s) {
    unsigned u = ((unsigned)(unsigned short)s) << 16;
    return __builtin_bit_cast(float, u);
}
__device__ __forceinline__ short f2b(float f) {
    unsigned u = __builtin_bit_cast(unsigned, f);
    unsigned r = u + 0x7FFFu + ((u >> 16) & 1u);
    return (short)(r >> 16);
}

__device__ __forceinline__ void lds16(const short* g, short* l) {
    __builtin_amdgcn_global_load_lds(
        (const __attribute__((address_space(1))) void*)g,
        (__attribute__((address_space(3))) void*)l, 16, 0, 0);
}

// ---------------- fp32 -> bf16 convert ----------------
__global__ __launch_bounds__(256) void cvt_kernel(const float* __restrict__ in,
                                                  short* __restrict__ out, int n4) {
    int i = blockIdx.x * 256 + threadIdx.x;
    if (i < n4) {
        float4 v = ((const float4*)in)[i];
        s16x4 o;
        o.x = f2b(v.x); o.y = f2b(v.y); o.z = f2b(v.z); o.w = f2b(v.w);
        ((s16x4*)out)[i] = o;
    }
}

// ---------------- RoPE trig table: [L][D/2] (cos, sin) ----------------
__global__ __launch_bounds__(256) void trig_kernel(float2* __restrict__ tab) {
    int i = blockIdx.x * 256 + threadIdx.x;   // L * 64 = 131072
    if (i < L_ * 64) {
        int l = i >> 6, f = i & 63;
        float inv = expf(-(float)(2 * f) * (9.210340371976184f / 128.f));
        float ang = (float)l * inv;
        tab[i] = make_float2(cosf(ang), sinf(ang));
    }
}

// ---------------- GEMM 256x256, BK=32, 4-buf counted-vmcnt, 2-phase fine interleave ----------------
// T3+T4 schedule: per K-tile, two {ds_read || stage-issue -> barrier ->
// lgkmcnt(0) -> 16 MFMA -> barrier} phases; vmcnt(8) counted once per K-tile
// (never 0 in steady state). Race-free: stage(t+3) writes buf (t-1)&3, dead
// past t's ph1 leading barrier; t+1's loads guaranteed by the counted vmcnt.
__global__ __launch_bounds__(512, 2)
void gemm256_bt(const short* __restrict__ A, const short* __restrict__ Bm,
                const float* __restrict__ bias, short* __restrict__ C,
                int M, int N, int K) {
    __shared__ __align__(16) short lds[4 * 16384];   // 4 bufs x (A 16KB + B 16KB)
    const int t0 = threadIdx.x;
    const int wid = t0 >> 6, lane = t0 & 63;
    const int fr = lane & 15, kg = lane >> 4;
    const int wr = wid >> 2, wc = wid & 3;           // 2M x 4N waves
    const int wg = blockIdx.x;
    const int swz = (wg & 7) * 48 + (wg >> 3);       // XCD swizzle (384 = 8*48)
    const int m0 = (swz & 15) << 8, n0 = (swz >> 4) << 8;

    // staging: inverse-swizzled global col, linear LDS dest (rule #21)
    const int srow = (lane >> 2);
    const int scol = ((lane & 3) ^ ((lane >> 3) & 3)) * 8;
    const short* aS0 = A  + (size_t)(m0 + wid * 32 + srow) * K + scol;
    const short* aS1 = aS0 + (size_t)16 * K;
    const short* bS0 = Bm + (size_t)(n0 + wid * 32 + srow) * K + scol;
    const short* bS1 = bS0 + (size_t)16 * K;
    short* const ldsW = lds + wid * 1024;

#define STAGE_A(tt, jj) {                                       \
        const size_t ko = (size_t)(tt) * 32;                    \
        short* la = ldsW + (jj) * 16384;                        \
        lds16(aS0 + ko, la);                                    \
        lds16(aS1 + ko, la + 512);                              \
    }
#define STAGE_B(tt, jj) {                                       \
        const size_t ko = (size_t)(tt) * 32;                    \
        short* lb = ldsW + (jj) * 16384 + 8192;                 \
        lds16(bS0 + ko, lb);                                    \
        lds16(bS1 + ko, lb + 512);                              \
    }

    f32x4 acc[8][4] = {};
    const int nt = K >> 5;                           // 64 K-tiles
    const int sw = (kg ^ ((fr >> 1) & 3)) << 4;      // read-side swizzled slot

    STAGE_A(0, 0); STAGE_B(0, 0);
    STAGE_A(1, 1); STAGE_B(1, 1);
    STAGE_A(2, 2); STAGE_B(2, 2);
    asm volatile("s_waitcnt vmcnt(8)" ::: "memory"); // tile 0 resident
    __builtin_amdgcn_s_barrier();
    __builtin_amdgcn_sched_barrier(0);

    for (int t = 0; t < nt; ++t) {
        const int rem = nt - 1 - t;
        const char* Ab = (const char*)(lds + (t & 3) * 16384);
        const char* Bb = Ab + 16384;
        s16x8 af[4], bf[4];
        // ---------- phase 1: reads (A mi0-3, B all) || stage A(t+3) ----------
#pragma unroll
        for (int mi = 0; mi < 4; mi++)
            af[mi] = *(const s16x8*)(Ab + (wr * 128 + mi * 16 + fr) * 64 + sw);
#pragma unroll
        for (int ni = 0; ni < 4; ni++)
            bf[ni] = *(const s16x8*)(Bb + (wc * 64 + ni * 16 + fr) * 64 + sw);
        if (rem >= 3) STAGE_A(t + 3, (t + 3) & 3);
        __builtin_amdgcn_s_barrier();
        asm volatile("s_waitcnt lgkmcnt(0)" ::: "memory");
        __builtin_amdgcn_sched_barrier(0);
        __builtin_amdgcn_s_setprio(1);
#pragma unroll
        for (int mi = 0; mi < 4; mi++)
#pragma unroll
            for (int ni = 0; ni < 4; ni++)
                acc[mi][ni] = __builtin_amdgcn_mfma_f32_16x16x32_bf16(af[mi], bf[ni], acc[mi][ni], 0, 0, 0);
        __builtin_amdgcn_s_setprio(0);
        __builtin_amdgcn_s_barrier();
        __builtin_amdgcn_sched_barrier(0);
        // ---------- phase 2: reads (A mi4-7) || stage B(t+3) ----------
#pragma unroll
        for (int mi = 0; mi < 4; mi++)
            af[mi] = *(const s16x8*)(Ab + (wr * 128 + (mi + 4) * 16 + fr) * 64 + sw);
        if (rem >= 3) STAGE_B(t + 3, (t + 3) & 3);
        __builtin_amdgcn_s_barrier();
        asm volatile("s_waitcnt lgkmcnt(0)" ::: "memory");
        __builtin_amdgcn_sched_barrier(0);
        __builtin_amdgcn_s_setprio(1);
#pragma unroll
        for (int mi = 0; mi < 4; mi++)
#pragma unroll
            for (int ni = 0; ni < 4; ni++)
                acc[mi + 4][ni] = __builtin_amdgcn_mfma_f32_16x16x32_bf16(af[mi], bf[ni], acc[mi + 4][ni], 0, 0, 0);
        __builtin_amdgcn_s_setprio(0);
        if (rem >= 3)      asm volatile("s_waitcnt vmcnt(8)" ::: "memory");
        else if (rem == 2) asm volatile("s_waitcnt vmcnt(4)" ::: "memory");
        else if (rem == 1) asm volatile("s_waitcnt vmcnt(0)" ::: "memory");
        __builtin_amdgcn_s_barrier();
        __builtin_amdgcn_sched_barrier(0);
    }
#undef STAGE_A
#undef STAGE_B
    // epilogue: C/D layout col = lane&15, row = kg*4 + r
#pragma unroll
    for (int mi = 0; mi < 8; mi++) {
#pragma unroll
        for (int ni = 0; ni < 4; ni++) {
            int gn = n0 + wc * 64 + ni * 16 + fr;
            float bv = bias[gn];
#pragma unroll
            for (int r = 0; r < 4; r++) {
                int gm = m0 + wr * 128 + mi * 16 + kg * 4 + r;
                C[(size_t)gm * N + gn] = f2b(acc[mi][ni][r] + bv);
            }
        }
    }
}

// ---------------- GEMM C[M,N] = A[M,K] * B[N,K]^T + bias (m97 structure + T2 swizzle) ----------------
template<int OUT_BF16>
__global__ __launch_bounds__(256, 2)
void gemm_bt(const short* __restrict__ A, const short* __restrict__ Bm,
             const float* __restrict__ bias, void* __restrict__ Cv,
             int M, int N, int K) {
    __shared__ __align__(16) short As[128 * 32];
    __shared__ __align__(16) short Bs[128 * 32];
    const int t = threadIdx.x;
    const int wid = t >> 6, lane = t & 63;
    const int fr = lane & 15, kg = lane >> 4;
    const int m0 = blockIdx.x * 128, n0 = blockIdx.y * 128;
    const int wm = (wid >> 1) * 64, wn = (wid & 1) * 64;
    f32x4 acc[4][4] = {};
    const int srow = wid * 16 + (lane >> 2);
    const int skk = ((lane & 3) ^ ((lane >> 3) & 3)) * 8;   // pre-swizzled k-col
    const int sw = kg ^ ((fr >> 1) & 3);                    // read-side slot
    const short* ga = A + (size_t)(m0 + srow) * K + skk;
    const short* gb = Bm + (size_t)(n0 + srow) * K + skk;
    short* lA0 = As + wid * 512;
    short* lA1 = As + 2048 + wid * 512;
    short* lB0 = Bs + wid * 512;
    short* lB1 = Bs + 2048 + wid * 512;

    for (int kt = 0; kt < K; kt += 32) {
        lds16(ga + kt, lA0);
        lds16(ga + kt + (size_t)64 * K, lA1);
        lds16(gb + kt, lB0);
        lds16(gb + kt + (size_t)64 * K, lB1);
        __syncthreads();
        s16x8 af[4], bf[4];
#pragma unroll
        for (int i = 0; i < 4; i++) {
            af[i] = *(const s16x8*)(As + (wm + i * 16 + fr) * 32 + sw * 8);
            bf[i] = *(const s16x8*)(Bs + (wn + i * 16 + fr) * 32 + sw * 8);
        }
#pragma unroll
        for (int mi = 0; mi < 4; mi++)
#pragma unroll
            for (int ni = 0; ni < 4; ni++)
                acc[mi][ni] = __builtin_amdgcn_mfma_f32_16x16x32_bf16(af[mi], bf[ni], acc[mi][ni], 0, 0, 0);
        __syncthreads();
    }
#pragma unroll
    for (int mi = 0; mi < 4; mi++) {
#pragma unroll
        for (int ni = 0; ni < 4; ni++) {
            int gn = n0 + wn + ni * 16 + fr;
            float bv = bias[gn];
#pragma unroll
            for (int r = 0; r < 4; r++) {
                int gm = m0 + wm + mi * 16 + kg * 4 + r;
                float v = acc[mi][ni][r] + bv;
                if (OUT_BF16)
                    ((short*)Cv)[(size_t)gm * N + gn] = f2b(v);
                else
                    ((float*)Cv)[(size_t)gm * N + gn] = v;
            }
        }
    }
}

// ---------------- rearrange qkv (B,L,3E) -> q,k (B,H,L,D) w/ RoPE; v -> (B,H,D,L) ----------------
// q is pre-scaled by 1/sqrt(D) so attn skips the per-element score scale.
__global__ __launch_bounds__(256)
void rearrange_rope(const short* __restrict__ qkv, const float2* __restrict__ trig,
                    short* __restrict__ q, short* __restrict__ k, short* __restrict__ vt) {
    __shared__ __align__(16) short vtile[64 * 128];
    const int t = threadIdx.x;
    const int bid = blockIdx.x;      // (bh)*32 + ltile
    const int l0 = (bid & 31) << 6;
    const int bh = bid >> 5;
    const int b = bh >> 4, h = bh & 15;
    const int rr = t >> 4, c16 = t & 15;

#pragma unroll
    for (int part = 0; part < 2; part++) {
        short* dst = part ? k : q;
        const float qs = part ? 1.0f : 0.08838834764831845f;
#pragma unroll
        for (int rb = 0; rb < 4; rb++) {
            int l = l0 + rb * 16 + rr;
            const short* p = qkv + ((size_t)(b * L_ + l)) * (3 * E_) + part * E_ + h * D_ + c16 * 8;
            s16x8 v = *(const s16x8*)p;
            float2 cs[4];
#pragma unroll
            for (int jj = 0; jj < 4; jj++) cs[jj] = trig[l * 64 + c16 * 4 + jj];
            s16x8 o;
#pragma unroll
            for (int jj = 0; jj < 4; jj++) {
                float x0 = b2f(v[2 * jj]), x1 = b2f(v[2 * jj + 1]);
                o[2 * jj]     = f2b((x0 * cs[jj].x - x1 * cs[jj].y) * qs);
                o[2 * jj + 1] = f2b((x1 * cs[jj].x + x0 * cs[jj].y) * qs);
            }
            *(s16x8*)(dst + ((size_t)bh * L_ + l) * D_ + c16 * 8) = o;
        }
    }
#pragma unroll
    for (int rb = 0; rb < 4; rb++) {
        int lr = rb * 16 + rr;
        const short* p = qkv + ((size_t)(b * L_ + l0 + lr)) * (3 * E_) + 2 * E_ + h * D_ + c16 * 8;
        s16x8 v = *(const s16x8*)p;
        int sw = ((lr & 7) ^ (lr >> 3)) << 4;
        *(s16x8*)((char*)vtile + lr * 256 + ((c16 * 16) ^ sw)) = v;
    }
    __syncthreads();
#pragma unroll
    for (int pass = 0; pass < 4; pass++) {
        int d = pass * 32 + (t >> 3);
        int lg = t & 7;
        s16x8 o;
#pragma unroll
        for (int jj = 0; jj < 8; jj++) {
            int row = lg * 8 + jj;
            int sw = ((row & 7) ^ (row >> 3)) << 4;
            o[jj] = *(const short*)((char*)vtile + row * 256 + ((d * 2) ^ sw));
        }
        *(s16x8*)(vt + ((size_t)bh * D_ + d) * L_ + l0 + lg * 8) = o;
    }
}

// ---------------- causal flash attention (round-2 structure + VALU diet) ----------------
__global__ __launch_bounds__(256)
void attn_kernel(const short* __restrict__ Q, const short* __restrict__ Kb,
                 const short* __restrict__ Vt, short* __restrict__ O) {
    __shared__ __align__(16) short Ks[2][64 * 128];   // [s][d] swizzled, dbuf
    __shared__ __align__(16) short Vs[2][128 * 64];   // [d][s] swizzled, dbuf
    __shared__ __align__(16) short Ps[4 * 16 * 64];   // per-wave [16][64] swizzled
    const int t = threadIdx.x;
    const int wid = t >> 6, lane = t & 63;
    const int fr = lane & 15, kg = lane >> 4;
    const int bid = blockIdx.x;
    const int xi = bid & 31, bh = bid >> 5;
    const int qt = ((bid >> 8) & 1) ? (31 - xi) : xi;
    const int q0 = qt << 6;
    const int b = bh >> 4, h = bh & 15;
    const size_t base = (size_t)bh * (L_ * D_);

    const int rr = t >> 4, c16 = t & 15;      // K staging map
    const int dr = t >> 3, lg2 = t & 7;       // V staging map

    s16x8 qa[4];
    {
        const short* qp = Q + base + (size_t)(q0 + wid * 16 + fr) * D_ + kg * 8;
#pragma unroll
        for (int ch = 0; ch < 4; ch++) qa[ch] = *(const s16x8*)(qp + ch * 32);
    }
    f32x4 oacc[8] = {};
    float mrow[4], lrow[4];
#pragma unroll
    for (int r = 0; r < 4; r++) { mrow[r] = -1e30f; lrow[r] = 0.f; }

    s16x8 kreg[4], vreg[4];
#pragma unroll
    for (int it = 0; it < 4; it++) {
        kreg[it] = *(const s16x8*)(Kb + base + (size_t)(it * 16 + rr) * D_ + c16 * 8);
        vreg[it] = *(const s16x8*)(Vt + base + (size_t)(it * 32 + dr) * L_ + lg2 * 8);
    }
#pragma unroll
    for (int it = 0; it < 4; it++) {
        int row = it * 16 + rr;
        *(s16x8*)((char*)Ks[0] + row * 256 + ((c16 * 16) ^ ((row & 7) << 4))) = kreg[it];
        int d = it * 32 + dr;
        *(s16x8*)((char*)Vs[0] + d * 128 + ((lg2 * 16) ^ ((d & 7) << 4))) = vreg[it];
    }
    __syncthreads();

    int cur = 0;
    for (int s0 = 0; s0 <= q0; s0 += 64) {
        const bool more = (s0 + 64 <= q0);
        if (more) {
            const int sn = s0 + 64;
#pragma unroll
            for (int it = 0; it < 4; it++) {
                kreg[it] = *(const s16x8*)(Kb + base + (size_t)(sn + it * 16 + rr) * D_ + c16 * 8);
                vreg[it] = *(const s16x8*)(Vt + base + (size_t)(it * 32 + dr) * L_ + sn + lg2 * 8);
            }
        }
        const short* KsC = Ks[cur];
        const short* VsC = Vs[cur];
        f32x4 sacc[4] = {};
        __builtin_amdgcn_s_setprio(1);
#pragma unroll
        for (int ch = 0; ch < 4; ch++) {
#pragma unroll
            for (int ni = 0; ni < 4; ni++) {
                int row = ni * 16 + fr;
                s16x8 kf = *(const s16x8*)((char*)KsC + row * 256 +
                                           ((ch * 64 + kg * 16) ^ ((row & 7) << 4)));
                sacc[ni] = __builtin_amdgcn_mfma_f32_16x16x32_bf16(qa[ch], kf, sacc[ni], 0, 0, 0);
            }
        }
        __builtin_amdgcn_s_setprio(0);
        const bool diag = (s0 == q0);
        float sv[4][4];
        float tm[4] = {-1e30f, -1e30f, -1e30f, -1e30f};
#pragma unroll
        for (int ni = 0; ni < 4; ni++)
#pragma unroll
            for (int r = 0; r < 4; r++) {
                float x = sacc[ni][r];
                if (diag && (ni * 16 + fr > wid * 16 + kg * 4 + r)) x = -1e30f;
                sv[ni][r] = x;
                tm[r] = fmaxf(tm[r], x);
            }
#pragma unroll
        for (int r = 0; r < 4; r++)
#pragma unroll
            for (int off = 1; off < 16; off <<= 1)
                tm[r] = fmaxf(tm[r], __shfl_xor(tm[r], off));
        int ok = 1;
#pragma unroll
        for (int r = 0; r < 4; r++) ok &= (tm[r] <= mrow[r] + 8.0f);
        if (!__all(ok)) {
#pragma unroll
            for (int r = 0; r < 4; r++) {
                float mnew = fmaxf(mrow[r], tm[r]);
                float sc = __expf(mrow[r] - mnew);
                mrow[r] = mnew;
                lrow[r] *= sc;
#pragma unroll
                for (int di = 0; di < 8; di++) oacc[di][r] *= sc;
            }
        }
#pragma unroll
        for (int ni = 0; ni < 4; ni++)
#pragma unroll
            for (int r = 0; r < 4; r++) {
                float p = __expf(sv[ni][r] - mrow[r]);
                sv[ni][r] = p;
                lrow[r] += p;
            }
#pragma unroll
        for (int ni = 0; ni < 4; ni++)
#pragma unroll
            for (int r = 0; r < 4; r++) {
                int row = kg * 4 + r;
                int cb = (ni * 16 + fr) * 2;
                *(short*)((char*)Ps + wid * 2048 + row * 128 + (cb ^ ((row & 7) << 4))) =
                    f2b(sv[ni][r]);
            }
        s16x8 pa[2];
#pragma unroll
        for (int sc2 = 0; sc2 < 2; sc2++)
            pa[sc2] = *(const s16x8*)((char*)Ps + wid * 2048 + fr * 128 +
                                      ((sc2 * 64 + kg * 16) ^ ((fr & 7) << 4)));
        __builtin_amdgcn_s_setprio(1);
#pragma unroll
        for (int di = 0; di < 8; di++) {
            int row = di * 16 + fr;
#pragma unroll
            for (int sc2 = 0; sc2 < 2; sc2++) {
                s16x8 vf = *(const s16x8*)((char*)VsC + row * 128 +
                                           ((sc2 * 64 + kg * 16) ^ ((row & 7) << 4)));
                oacc[di] = __builtin_amdgcn_mfma_f32_16x16x32_bf16(pa[sc2], vf, oacc[di], 0, 0, 0);
            }
        }
        __builtin_amdgcn_s_setprio(0);
        if (more) {
            short* KsN = Ks[cur ^ 1];
            short* VsN = Vs[cur ^ 1];
#pragma unroll
            for (int it = 0; it < 4; it++) {
                int row = it * 16 + rr;
                *(s16x8*)((char*)KsN + row * 256 + ((c16 * 16) ^ ((row & 7) << 4))) = kreg[it];
                int d = it * 32 + dr;
                *(s16x8*)((char*)VsN + d * 128 + ((lg2 * 16) ^ ((d & 7) << 4))) = vreg[it];
            }
        }
        __syncthreads();
        cur ^= 1;
    }
#pragma unroll
    for (int r = 0; r < 4; r++)
#pragma unroll
        for (int off = 1; off < 16; off <<= 1)
            lrow[r] += __shfl_xor(lrow[r], off);
#pragma unroll
    for (int r = 0; r < 4; r++) {
        float rl = 1.f / lrow[r];
        int qg = q0 + wid * 16 + kg * 4 + r;
        size_t orow = (size_t)(b * L_ + qg) * E_ + h * D_;
#pragma unroll
        for (int di = 0; di < 8; di++)
            O[orow + di * 16 + fr] = f2b(oacc[di][r] * rl);
    }
}

extern "C" void kernel_launch(void* const* d_in, const int* in_sizes, int n_in,
                              void* d_out, int out_size, void* d_ws, size_t ws_size,
                              hipStream_t stream) {
    const float* x     = (const float*)d_in[0];
    const float* wqkv  = (const float*)d_in[1];
    const float* bqkv  = (const float*)d_in[2];
    const float* wout  = (const float*)d_in[3];
    const float* bout  = (const float*)d_in[4];
    float* out = (float*)d_out;
    char* ws = (char*)d_ws;

    const size_t SZ_XB    = (size_t)4096 * 2048 * 2;
    const size_t SZ_WQKV  = (size_t)6144 * 2048 * 2;
    const size_t SZ_WOUT  = (size_t)2048 * 2048 * 2;
    const size_t SZ_QKV   = (size_t)4096 * 6144 * 2;
    const size_t SZ_HLD   = (size_t)32 * 2048 * 128 * 2;
    short* xb    = (short*)(ws);
    short* wqkvb = (short*)(ws + SZ_XB);
    short* woutb = (short*)(ws + SZ_XB + SZ_WQKV);
    short* qkvb  = (short*)(ws + SZ_XB + SZ_WQKV + SZ_WOUT);
    short* qb    = (short*)(ws + SZ_XB + SZ_WQKV + SZ_WOUT + SZ_QKV);
    short* kb    = (short*)(ws + SZ_XB + SZ_WQKV + SZ_WOUT + SZ_QKV + SZ_HLD);
    short* vtb   = (short*)(ws + SZ_XB + SZ_WQKV + SZ_WOUT + SZ_QKV + 2 * SZ_HLD);
    float2* trig = (float2*)(ws + SZ_XB + SZ_WQKV + SZ_WOUT + SZ_QKV + 3 * SZ_HLD);
    short* ob    = xb;  // alias: xb dead after GEMM1
    const size_t NEEDED = SZ_XB + SZ_WQKV + SZ_WOUT + SZ_QKV + 3 * SZ_HLD + (size_t)L_ * 64 * 8;
    if (ws_size < NEEDED) return;

    cvt_kernel<<<8192, 256, 0, stream>>>(x, xb, 2097152);
    cvt_kernel<<<12288, 256, 0, stream>>>(wqkv, wqkvb, 3145728);
    cvt_kernel<<<4096, 256, 0, stream>>>(wout, woutb, 1048576);
    trig_kernel<<<512, 256, 0, stream>>>(trig);

    gemm256_bt<<<384, 512, 0, stream>>>(xb, wqkvb, bqkv, qkvb, 4096, 6144, 2048);
    rearrange_rope<<<1024, 256, 0, stream>>>(qkvb, trig, qb, kb, vtb);
    attn_kernel<<<1024, 256, 0, stream>>>(qb, kb, vtb, ob);
    gemm_bt<0><<<dim3(32, 16), 256, 0, stream>>>(ob, woutb, bout, (void*)out, 4096, 2048, 2048);
}

// Round 9
// 322.947 us; speedup vs baseline: 1.0624x; 1.0624x over previous
//
#include <hip/hip_runtime.h>
#include <hip/hip_bf16.h>

typedef __attribute__((ext_vector_type(8))) short s16x8;
typedef __attribute__((ext_vector_type(4))) short s16x4;
typedef __attribute__((ext_vector_type(4))) float f32x4;

#define B_ 2
#define L_ 2048
#define E_ 2048
#define H_ 16
#define D_ 128

__device__ __forceinline__ float b2f(short s) {
    unsigned u = ((unsigned)(unsigned short)s) << 16;
    return __builtin_bit_cast(float, u);
}
__device__ __forceinline__ short f2b(float f) {
    unsigned u = __builtin_bit_cast(unsigned, f);
    unsigned r = u + 0x7FFFu + ((u >> 16) & 1u);
    return (short)(r >> 16);
}

__device__ __forceinline__ void lds16(const short* g, short* l) {
    __builtin_amdgcn_global_load_lds(
        (const __attribute__((address_space(1))) void*)g,
        (__attribute__((address_space(3))) void*)l, 16, 0, 0);
}

// ---------------- fp32 -> bf16 convert ----------------
__global__ __launch_bounds__(256) void cvt_kernel(const float* __restrict__ in,
                                                  short* __restrict__ out, int n4) {
    int i = blockIdx.x * 256 + threadIdx.x;
    if (i < n4) {
        float4 v = ((const float4*)in)[i];
        s16x4 o;
        o.x = f2b(v.x); o.y = f2b(v.y); o.z = f2b(v.z); o.w = f2b(v.w);
        ((s16x4*)out)[i] = o;
    }
}

// ---------------- RoPE trig table: [L][D/2] (cos, sin) ----------------
__global__ __launch_bounds__(256) void trig_kernel(float2* __restrict__ tab) {
    int i = blockIdx.x * 256 + threadIdx.x;   // L * 64 = 131072
    if (i < L_ * 64) {
        int l = i >> 6, f = i & 63;
        float inv = expf(-(float)(2 * f) * (9.210340371976184f / 128.f));
        float ang = (float)l * inv;
        tab[i] = make_float2(cosf(ang), sinf(ang));
    }
}

// ---------------- GEMM C[M,N] = A[M,K] * B[N,K]^T + bias (m97 structure + T2 swizzle) ----------------
// 128^2 tile, 4 waves, ~2.7 blocks/CU: inter-block overlap covers the stage
// drain (m97/m114 regime). Swizzle: read slot sw = kg ^ ((fr>>1)&3) over 64 B
// rows -> 2-way bank aliasing (free); global source pre-swizzled, LDS linear.
template<int OUT_BF16>
__global__ __launch_bounds__(256, 2)
void gemm_bt(const short* __restrict__ A, const short* __restrict__ Bm,
             const float* __restrict__ bias, void* __restrict__ Cv,
             int M, int N, int K) {
    __shared__ __align__(16) short As[128 * 32];
    __shared__ __align__(16) short Bs[128 * 32];
    const int t = threadIdx.x;
    const int wid = t >> 6, lane = t & 63;
    const int fr = lane & 15, kg = lane >> 4;
    const int m0 = blockIdx.x * 128, n0 = blockIdx.y * 128;
    const int wm = (wid >> 1) * 64, wn = (wid & 1) * 64;
    f32x4 acc[4][4] = {};
    const int srow = wid * 16 + (lane >> 2);
    const int skk = ((lane & 3) ^ ((lane >> 3) & 3)) * 8;   // pre-swizzled k-col
    const int sw = kg ^ ((fr >> 1) & 3);                    // read-side slot
    const short* ga = A + (size_t)(m0 + srow) * K + skk;
    const short* gb = Bm + (size_t)(n0 + srow) * K + skk;
    short* lA0 = As + wid * 512;
    short* lA1 = As + 2048 + wid * 512;
    short* lB0 = Bs + wid * 512;
    short* lB1 = Bs + 2048 + wid * 512;

    for (int kt = 0; kt < K; kt += 32) {
        lds16(ga + kt, lA0);
        lds16(ga + kt + (size_t)64 * K, lA1);
        lds16(gb + kt, lB0);
        lds16(gb + kt + (size_t)64 * K, lB1);
        __syncthreads();
        s16x8 af[4], bf[4];
#pragma unroll
        for (int i = 0; i < 4; i++) {
            af[i] = *(const s16x8*)(As + (wm + i * 16 + fr) * 32 + sw * 8);
            bf[i] = *(const s16x8*)(Bs + (wn + i * 16 + fr) * 32 + sw * 8);
        }
#pragma unroll
        for (int mi = 0; mi < 4; mi++)
#pragma unroll
            for (int ni = 0; ni < 4; ni++)
                acc[mi][ni] = __builtin_amdgcn_mfma_f32_16x16x32_bf16(af[mi], bf[ni], acc[mi][ni], 0, 0, 0);
        __syncthreads();
    }
#pragma unroll
    for (int mi = 0; mi < 4; mi++) {
#pragma unroll
        for (int ni = 0; ni < 4; ni++) {
            int gn = n0 + wn + ni * 16 + fr;
            float bv = bias[gn];
#pragma unroll
            for (int r = 0; r < 4; r++) {
                int gm = m0 + wm + mi * 16 + kg * 4 + r;
                float v = acc[mi][ni][r] + bv;
                if (OUT_BF16)
                    ((short*)Cv)[(size_t)gm * N + gn] = f2b(v);
                else
                    ((float*)Cv)[(size_t)gm * N + gn] = v;
            }
        }
    }
}

// ---------------- rearrange qkv (B,L,3E) -> q,k (B,H,L,D) w/ RoPE; v -> (B,H,D,L) ----------------
// q is pre-scaled by 1/sqrt(D) so attn skips the per-element score scale.
__global__ __launch_bounds__(256)
void rearrange_rope(const short* __restrict__ qkv, const float2* __restrict__ trig,
                    short* __restrict__ q, short* __restrict__ k, short* __restrict__ vt) {
    __shared__ __align__(16) short vtile[64 * 128];
    const int t = threadIdx.x;
    const int bid = blockIdx.x;      // (bh)*32 + ltile
    const int l0 = (bid & 31) << 6;
    const int bh = bid >> 5;
    const int b = bh >> 4, h = bh & 15;
    const int rr = t >> 4, c16 = t & 15;

#pragma unroll
    for (int part = 0; part < 2; part++) {
        short* dst = part ? k : q;
        const float qs = part ? 1.0f : 0.08838834764831845f;
#pragma unroll
        for (int rb = 0; rb < 4; rb++) {
            int l = l0 + rb * 16 + rr;
            const short* p = qkv + ((size_t)(b * L_ + l)) * (3 * E_) + part * E_ + h * D_ + c16 * 8;
            s16x8 v = *(const s16x8*)p;
            float2 cs[4];
#pragma unroll
            for (int jj = 0; jj < 4; jj++) cs[jj] = trig[l * 64 + c16 * 4 + jj];
            s16x8 o;
#pragma unroll
            for (int jj = 0; jj < 4; jj++) {
                float x0 = b2f(v[2 * jj]), x1 = b2f(v[2 * jj + 1]);
                o[2 * jj]     = f2b((x0 * cs[jj].x - x1 * cs[jj].y) * qs);
                o[2 * jj + 1] = f2b((x1 * cs[jj].x + x0 * cs[jj].y) * qs);
            }
            *(s16x8*)(dst + ((size_t)bh * L_ + l) * D_ + c16 * 8) = o;
        }
    }
#pragma unroll
    for (int rb = 0; rb < 4; rb++) {
        int lr = rb * 16 + rr;
        const short* p = qkv + ((size_t)(b * L_ + l0 + lr)) * (3 * E_) + 2 * E_ + h * D_ + c16 * 8;
        s16x8 v = *(const s16x8*)p;
        int sw = ((lr & 7) ^ (lr >> 3)) << 4;
        *(s16x8*)((char*)vtile + lr * 256 + ((c16 * 16) ^ sw)) = v;
    }
    __syncthreads();
#pragma unroll
    for (int pass = 0; pass < 4; pass++) {
        int d = pass * 32 + (t >> 3);
        int lg = t & 7;
        s16x8 o;
#pragma unroll
        for (int jj = 0; jj < 8; jj++) {
            int row = lg * 8 + jj;
            int sw = ((row & 7) ^ (row >> 3)) << 4;
            o[jj] = *(const short*)((char*)vtile + row * 256 + ((d * 2) ^ sw));
        }
        *(s16x8*)(vt + ((size_t)bh * D_ + d) * L_ + l0 + lg * 8) = o;
    }
}

// ---------------- causal flash attention: single-buf K/V via global_load_lds ----------------
// 40 KB LDS -> 4 blocks/CU (16 waves/CU): the stage drain between barriers is
// covered by 3 other unsynchronized blocks (m97/m114 inter-block overlap).
// K/V LDS layouts identical to before; staging writes LINEAR LDS while the
// GLOBAL source column carries the swizzle (rule #21 involution).
__global__ __launch_bounds__(256)
void attn_kernel(const short* __restrict__ Q, const short* __restrict__ Kb,
                 const short* __restrict__ Vt, short* __restrict__ O) {
    __shared__ __align__(16) short Ks[64 * 128];   // [s][d] swizzled
    __shared__ __align__(16) short Vs[128 * 64];   // [d][s] swizzled
    __shared__ __align__(16) short Ps[4 * 16 * 64];
    const int t = threadIdx.x;
    const int wid = t >> 6, lane = t & 63;
    const int fr = lane & 15, kg = lane >> 4;
    const int bid = blockIdx.x;
    const int xi = bid & 31, bh = bid >> 5;
    const int qt = ((bid >> 8) & 1) ? (31 - xi) : xi;
    const int q0 = qt << 6;
    const int b = bh >> 4, h = bh & 15;
    const size_t base = (size_t)bh * (L_ * D_);

    // staging maps (global side carries the swizzle; LDS dest linear)
    const int kr = t >> 4, kc = t & 15;   // K: row kr+16c, 16B chunk kc
    const int vd = t >> 3, vl = t & 7;    // V: row vd+32c, 16B chunk vl

#define STAGEKV(s0v) {                                                        \
        _Pragma("unroll")                                                     \
        for (int c = 0; c < 4; c++) {                                         \
            int row = c * 16 + kr;                                            \
            int kcol = ((kc * 16) ^ ((row & 7) << 4)) >> 1;                   \
            lds16(Kb + base + (size_t)((s0v) + row) * D_ + kcol,              \
                  Ks + c * 2048 + wid * 512);                                 \
            int d = c * 32 + vd;                                              \
            int vcol = ((vl * 16) ^ ((d & 7) << 4)) >> 1;                     \
            lds16(Vt + base + (size_t)d * L_ + (s0v) + vcol,                  \
                  Vs + c * 2048 + wid * 512);                                 \
        }                                                                     \
    }

    s16x8 qa[4];
    {
        const short* qp = Q + base + (size_t)(q0 + wid * 16 + fr) * D_ + kg * 8;
#pragma unroll
        for (int ch = 0; ch < 4; ch++) qa[ch] = *(const s16x8*)(qp + ch * 32);
    }
    f32x4 oacc[8] = {};
    float mrow[4], lrow[4];
#pragma unroll
    for (int r = 0; r < 4; r++) { mrow[r] = -1e30f; lrow[r] = 0.f; }

    STAGEKV(0);
    __syncthreads();

    for (int s0 = 0; s0 <= q0; s0 += 64) {
        const bool more = (s0 + 64 <= q0);
        // QK^T: S (16q x 64s) per wave (scale pre-folded into Q)
        f32x4 sacc[4] = {};
        __builtin_amdgcn_s_setprio(1);
#pragma unroll
        for (int ch = 0; ch < 4; ch++) {
#pragma unroll
            for (int ni = 0; ni < 4; ni++) {
                int row = ni * 16 + fr;
                s16x8 kf = *(const s16x8*)((char*)Ks + row * 256 +
                                           ((ch * 64 + kg * 16) ^ ((row & 7) << 4)));
                sacc[ni] = __builtin_amdgcn_mfma_f32_16x16x32_bf16(qa[ch], kf, sacc[ni], 0, 0, 0);
            }
        }
        __builtin_amdgcn_s_setprio(0);
        // causal mask + per-row tile max
        const bool diag = (s0 == q0);
        float sv[4][4];
        float tm[4] = {-1e30f, -1e30f, -1e30f, -1e30f};
#pragma unroll
        for (int ni = 0; ni < 4; ni++)
#pragma unroll
            for (int r = 0; r < 4; r++) {
                float x = sacc[ni][r];
                if (diag && (ni * 16 + fr > wid * 16 + kg * 4 + r)) x = -1e30f;
                sv[ni][r] = x;
                tm[r] = fmaxf(tm[r], x);
            }
#pragma unroll
        for (int r = 0; r < 4; r++)
#pragma unroll
            for (int off = 1; off < 16; off <<= 1)
                tm[r] = fmaxf(tm[r], __shfl_xor(tm[r], off));
        // defer-max (T13)
        int ok = 1;
#pragma unroll
        for (int r = 0; r < 4; r++) ok &= (tm[r] <= mrow[r] + 8.0f);
        if (!__all(ok)) {
#pragma unroll
            for (int r = 0; r < 4; r++) {
                float mnew = fmaxf(mrow[r], tm[r]);
                float sc = __expf(mrow[r] - mnew);
                mrow[r] = mnew;
                lrow[r] *= sc;
#pragma unroll
                for (int di = 0; di < 8; di++) oacc[di][r] *= sc;
            }
        }
        // P = exp(S - m); per-lane partial row-sums (reduced after the loop)
#pragma unroll
        for (int ni = 0; ni < 4; ni++)
#pragma unroll
            for (int r = 0; r < 4; r++) {
                float p = __expf(sv[ni][r] - mrow[r]);
                sv[ni][r] = p;
                lrow[r] += p;
            }
        // write P (C-layout) to per-wave LDS, swizzled (wave-private)
#pragma unroll
        for (int ni = 0; ni < 4; ni++)
#pragma unroll
            for (int r = 0; r < 4; r++) {
                int row = kg * 4 + r;
                int cb = (ni * 16 + fr) * 2;
                *(short*)((char*)Ps + wid * 2048 + row * 128 + (cb ^ ((row & 7) << 4))) =
                    f2b(sv[ni][r]);
            }
        // PV: O (16q x 128d) += P (16x64) * V (64x128)
        s16x8 pa[2];
#pragma unroll
        for (int sc2 = 0; sc2 < 2; sc2++)
            pa[sc2] = *(const s16x8*)((char*)Ps + wid * 2048 + fr * 128 +
                                      ((sc2 * 64 + kg * 16) ^ ((fr & 7) << 4)));
        __builtin_amdgcn_s_setprio(1);
#pragma unroll
        for (int di = 0; di < 8; di++) {
            int row = di * 16 + fr;
#pragma unroll
            for (int sc2 = 0; sc2 < 2; sc2++) {
                s16x8 vf = *(const s16x8*)((char*)Vs + row * 128 +
                                           ((sc2 * 64 + kg * 16) ^ ((row & 7) << 4)));
                oacc[di] = __builtin_amdgcn_mfma_f32_16x16x32_bf16(pa[sc2], vf, oacc[di], 0, 0, 0);
            }
        }
        __builtin_amdgcn_s_setprio(0);
        __syncthreads();              // all waves done reading K/V of tile t
        if (more) STAGEKV(s0 + 64);   // overwrite; drain covered by other blocks
        __syncthreads();              // implicit vmcnt(0) before barrier
    }
#undef STAGEKV
    // deferred l reduce (within 16-lane row groups)
#pragma unroll
    for (int r = 0; r < 4; r++)
#pragma unroll
        for (int off = 1; off < 16; off <<= 1)
            lrow[r] += __shfl_xor(lrow[r], off);
    // epilogue
#pragma unroll
    for (int r = 0; r < 4; r++) {
        float rl = 1.f / lrow[r];
        int qg = q0 + wid * 16 + kg * 4 + r;
        size_t orow = (size_t)(b * L_ + qg) * E_ + h * D_;
#pragma unroll
        for (int di = 0; di < 8; di++)
            O[orow + di * 16 + fr] = f2b(oacc[di][r] * rl);
    }
}

extern "C" void kernel_launch(void* const* d_in, const int* in_sizes, int n_in,
                              void* d_out, int out_size, void* d_ws, size_t ws_size,
                              hipStream_t stream) {
    const float* x     = (const float*)d_in[0];
    const float* wqkv  = (const float*)d_in[1];
    const float* bqkv  = (const float*)d_in[2];
    const float* wout  = (const float*)d_in[3];
    const float* bout  = (const float*)d_in[4];
    float* out = (float*)d_out;
    char* ws = (char*)d_ws;

    const size_t SZ_XB    = (size_t)4096 * 2048 * 2;
    const size_t SZ_WQKV  = (size_t)6144 * 2048 * 2;
    const size_t SZ_WOUT  = (size_t)2048 * 2048 * 2;
    const size_t SZ_QKV   = (size_t)4096 * 6144 * 2;
    const size_t SZ_HLD   = (size_t)32 * 2048 * 128 * 2;
    short* xb    = (short*)(ws);
    short* wqkvb = (short*)(ws + SZ_XB);
    short* woutb = (short*)(ws + SZ_XB + SZ_WQKV);
    short* qkvb  = (short*)(ws + SZ_XB + SZ_WQKV + SZ_WOUT);
    short* qb    = (short*)(ws + SZ_XB + SZ_WQKV + SZ_WOUT + SZ_QKV);
    short* kb    = (short*)(ws + SZ_XB + SZ_WQKV + SZ_WOUT + SZ_QKV + SZ_HLD);
    short* vtb   = (short*)(ws + SZ_XB + SZ_WQKV + SZ_WOUT + SZ_QKV + 2 * SZ_HLD);
    float2* trig = (float2*)(ws + SZ_XB + SZ_WQKV + SZ_WOUT + SZ_QKV + 3 * SZ_HLD);
    short* ob    = xb;  // alias: xb dead after GEMM1
    const size_t NEEDED = SZ_XB + SZ_WQKV + SZ_WOUT + SZ_QKV + 3 * SZ_HLD + (size_t)L_ * 64 * 8;
    if (ws_size < NEEDED) return;

    cvt_kernel<<<8192, 256, 0, stream>>>(x, xb, 2097152);
    cvt_kernel<<<12288, 256, 0, stream>>>(wqkv, wqkvb, 3145728);
    cvt_kernel<<<4096, 256, 0, stream>>>(wout, woutb, 1048576);
    trig_kernel<<<512, 256, 0, stream>>>(trig);

    gemm_bt<1><<<dim3(32, 48), 256, 0, stream>>>(xb, wqkvb, bqkv, (void*)qkvb, 4096, 6144, 2048);
    rearrange_rope<<<1024, 256, 0, stream>>>(qkvb, trig, qb, kb, vtb);
    attn_kernel<<<1024, 256, 0, stream>>>(qb, kb, vtb, ob);
    gemm_bt<0><<<dim3(32, 16), 256, 0, stream>>>(ob, woutb, bout, (void*)out, 4096, 2048, 2048);
}

// Round 10
// 296.810 us; speedup vs baseline: 1.1560x; 1.0881x over previous
//
#include <hip/hip_runtime.h>
#include <hip/hip_bf16.h>

typedef __attribute__((ext_vector_type(8))) short s16x8;
typedef __attribute__((ext_vector_type(4))) short s16x4;
typedef __attribute__((ext_vector_type(4))) float f32x4;

#define B_ 2
#define L_ 2048
#define E_ 2048
#define H_ 16
#define D_ 128

__device__ __forceinline__ float b2f(short s) {
    unsigned u = ((unsigned)(unsigned short)s) << 16;
    return __builtin_bit_cast(float, u);
}
__device__ __forceinline__ short f2b(float f) {
    unsigned u = __builtin_bit_cast(unsigned, f);
    unsigned r = u + 0x7FFFu + ((u >> 16) & 1u);
    return (short)(r >> 16);
}

__device__ __forceinline__ void lds16(const short* g, short* l) {
    __builtin_amdgcn_global_load_lds(
        (const __attribute__((address_space(1))) void*)g,
        (__attribute__((address_space(3))) void*)l, 16, 0, 0);
}

// ---------------- fp32 -> bf16 convert ----------------
__global__ __launch_bounds__(256) void cvt_kernel(const float* __restrict__ in,
                                                  short* __restrict__ out, int n4) {
    int i = blockIdx.x * 256 + threadIdx.x;
    if (i < n4) {
        float4 v = ((const float4*)in)[i];
        s16x4 o;
        o.x = f2b(v.x); o.y = f2b(v.y); o.z = f2b(v.z); o.w = f2b(v.w);
        ((s16x4*)out)[i] = o;
    }
}

// ---------------- RoPE trig table: [L][D/2] (cos, sin) ----------------
__global__ __launch_bounds__(256) void trig_kernel(float2* __restrict__ tab) {
    int i = blockIdx.x * 256 + threadIdx.x;   // L * 64 = 131072
    if (i < L_ * 64) {
        int l = i >> 6, f = i & 63;
        float inv = expf(-(float)(2 * f) * (9.210340371976184f / 128.f));
        float ang = (float)l * inv;
        tab[i] = make_float2(cosf(ang), sinf(ang));
    }
}

// ---------------- GEMM C[M,N] = A[M,K] * B[N,K]^T + bias (m97 structure + T2 swizzle) ----------------
template<int OUT_BF16>
__global__ __launch_bounds__(256, 2)
void gemm_bt(const short* __restrict__ A, const short* __restrict__ Bm,
             const float* __restrict__ bias, void* __restrict__ Cv,
             int M, int N, int K) {
    __shared__ __align__(16) short As[128 * 32];
    __shared__ __align__(16) short Bs[128 * 32];
    const int t = threadIdx.x;
    const int wid = t >> 6, lane = t & 63;
    const int fr = lane & 15, kg = lane >> 4;
    const int m0 = blockIdx.x * 128, n0 = blockIdx.y * 128;
    const int wm = (wid >> 1) * 64, wn = (wid & 1) * 64;
    f32x4 acc[4][4] = {};
    const int srow = wid * 16 + (lane >> 2);
    const int skk = ((lane & 3) ^ ((lane >> 3) & 3)) * 8;   // pre-swizzled k-col
    const int sw = kg ^ ((fr >> 1) & 3);                    // read-side slot
    const short* ga = A + (size_t)(m0 + srow) * K + skk;
    const short* gb = Bm + (size_t)(n0 + srow) * K + skk;
    short* lA0 = As + wid * 512;
    short* lA1 = As + 2048 + wid * 512;
    short* lB0 = Bs + wid * 512;
    short* lB1 = Bs + 2048 + wid * 512;

    for (int kt = 0; kt < K; kt += 32) {
        lds16(ga + kt, lA0);
        lds16(ga + kt + (size_t)64 * K, lA1);
        lds16(gb + kt, lB0);
        lds16(gb + kt + (size_t)64 * K, lB1);
        __syncthreads();
        s16x8 af[4], bf[4];
#pragma unroll
        for (int i = 0; i < 4; i++) {
            af[i] = *(const s16x8*)(As + (wm + i * 16 + fr) * 32 + sw * 8);
            bf[i] = *(const s16x8*)(Bs + (wn + i * 16 + fr) * 32 + sw * 8);
        }
#pragma unroll
        for (int mi = 0; mi < 4; mi++)
#pragma unroll
            for (int ni = 0; ni < 4; ni++)
                acc[mi][ni] = __builtin_amdgcn_mfma_f32_16x16x32_bf16(af[mi], bf[ni], acc[mi][ni], 0, 0, 0);
        __syncthreads();
    }
#pragma unroll
    for (int mi = 0; mi < 4; mi++) {
#pragma unroll
        for (int ni = 0; ni < 4; ni++) {
            int gn = n0 + wn + ni * 16 + fr;
            float bv = bias[gn];
#pragma unroll
            for (int r = 0; r < 4; r++) {
                int gm = m0 + wm + mi * 16 + kg * 4 + r;
                float v = acc[mi][ni][r] + bv;
                if (OUT_BF16)
                    ((short*)Cv)[(size_t)gm * N + gn] = f2b(v);
                else
                    ((float*)Cv)[(size_t)gm * N + gn] = v;
            }
        }
    }
}

// ---------------- rearrange qkv (B,L,3E) -> q,k (B,H,L,D) w/ RoPE; v -> (B,H,D,L) ----------------
// q is pre-scaled by 1/sqrt(D) so attn skips the per-element score scale.
__global__ __launch_bounds__(256)
void rearrange_rope(const short* __restrict__ qkv, const float2* __restrict__ trig,
                    short* __restrict__ q, short* __restrict__ k, short* __restrict__ vt) {
    __shared__ __align__(16) short vtile[64 * 128];
    const int t = threadIdx.x;
    const int bid = blockIdx.x;      // (bh)*32 + ltile
    const int l0 = (bid & 31) << 6;
    const int bh = bid >> 5;
    const int b = bh >> 4, h = bh & 15;
    const int rr = t >> 4, c16 = t & 15;

#pragma unroll
    for (int part = 0; part < 2; part++) {
        short* dst = part ? k : q;
        const float qs = part ? 1.0f : 0.08838834764831845f;
#pragma unroll
        for (int rb = 0; rb < 4; rb++) {
            int l = l0 + rb * 16 + rr;
            const short* p = qkv + ((size_t)(b * L_ + l)) * (3 * E_) + part * E_ + h * D_ + c16 * 8;
            s16x8 v = *(const s16x8*)p;
            float2 cs[4];
#pragma unroll
            for (int jj = 0; jj < 4; jj++) cs[jj] = trig[l * 64 + c16 * 4 + jj];
            s16x8 o;
#pragma unroll
            for (int jj = 0; jj < 4; jj++) {
                float x0 = b2f(v[2 * jj]), x1 = b2f(v[2 * jj + 1]);
                o[2 * jj]     = f2b((x0 * cs[jj].x - x1 * cs[jj].y) * qs);
                o[2 * jj + 1] = f2b((x1 * cs[jj].x + x0 * cs[jj].y) * qs);
            }
            *(s16x8*)(dst + ((size_t)bh * L_ + l) * D_ + c16 * 8) = o;
        }
    }
#pragma unroll
    for (int rb = 0; rb < 4; rb++) {
        int lr = rb * 16 + rr;
        const short* p = qkv + ((size_t)(b * L_ + l0 + lr)) * (3 * E_) + 2 * E_ + h * D_ + c16 * 8;
        s16x8 v = *(const s16x8*)p;
        int sw = ((lr & 7) ^ (lr >> 3)) << 4;
        *(s16x8*)((char*)vtile + lr * 256 + ((c16 * 16) ^ sw)) = v;
    }
    __syncthreads();
#pragma unroll
    for (int pass = 0; pass < 4; pass++) {
        int d = pass * 32 + (t >> 3);
        int lg = t & 7;
        s16x8 o;
#pragma unroll
        for (int jj = 0; jj < 8; jj++) {
            int row = lg * 8 + jj;
            int sw = ((row & 7) ^ (row >> 3)) << 4;
            o[jj] = *(const short*)((char*)vtile + row * 256 + ((d * 2) ^ sw));
        }
        *(s16x8*)(vt + ((size_t)bh * D_ + d) * L_ + l0 + lg * 8) = o;
    }
}

// ---------------- causal flash attention: uniform-work q-tile pairs + T14 reg-staging ----------------
// Each block processes q-tiles (qt, 31-qt) sequentially: exactly 33 kv-iters
// per block -> balanced under ANY block->CU mapping (dispatch order undefined).
// Staging: global->reg loads issued BEFORE compute (latency hides under
// QK/softmax/PV); only reg->LDS ds_write sits between the two barriers.
// Single 32KB K/V buffer + 8KB P = 40KB -> 4 blocks/CU capacity.
__global__ __launch_bounds__(256, 2)
void attn_kernel(const short* __restrict__ Q, const short* __restrict__ Kb,
                 const short* __restrict__ Vt, short* __restrict__ O) {
    __shared__ __align__(16) short Ks[64 * 128];   // [s][d] swizzled
    __shared__ __align__(16) short Vs[128 * 64];   // [d][s] swizzled
    __shared__ __align__(16) short Ps[4 * 16 * 64];
    const int t = threadIdx.x;
    const int wid = t >> 6, lane = t & 63;
    const int fr = lane & 15, kg = lane >> 4;
    const int bid = blockIdx.x;
    const int qp = bid & 15, bh = bid >> 4;   // 512 blocks: 16 pairs x 32 bh
    const int b = bh >> 4, h = bh & 15;
    const size_t base = (size_t)bh * (L_ * D_);

    const int rr = t >> 4, c16 = t & 15;      // K staging map
    const int dr = t >> 3, lg2 = t & 7;       // V staging map

    s16x8 kreg[4], vreg[4];
#define LOADKV(s0v) { _Pragma("unroll")                                        \
    for (int it = 0; it < 4; it++) {                                           \
        kreg[it] = *(const s16x8*)(Kb + base + (size_t)((s0v) + it * 16 + rr) * D_ + c16 * 8); \
        vreg[it] = *(const s16x8*)(Vt + base + (size_t)(it * 32 + dr) * L_ + (s0v) + lg2 * 8); \
    } }
#define WRITEKV() { _Pragma("unroll")                                          \
    for (int it = 0; it < 4; it++) {                                           \
        int row = it * 16 + rr;                                                \
        *(s16x8*)((char*)Ks + row * 256 + ((c16 * 16) ^ ((row & 7) << 4))) = kreg[it]; \
        int d = it * 32 + dr;                                                  \
        *(s16x8*)((char*)Vs + d * 128 + ((lg2 * 16) ^ ((d & 7) << 4))) = vreg[it]; \
    } }

    LOADKV(0);
    WRITEKV();
    __syncthreads();

    for (int ph = 0; ph < 2; ph++) {
        const int qt = ph ? (31 - qp) : qp;
        const int q0 = qt << 6;
        s16x8 qa[4];
        {
            const short* qptr = Q + base + (size_t)(q0 + wid * 16 + fr) * D_ + kg * 8;
#pragma unroll
            for (int ch = 0; ch < 4; ch++) qa[ch] = *(const s16x8*)(qptr + ch * 32);
        }
        f32x4 oacc[8] = {};
        float mrow[4], lrow[4];
#pragma unroll
        for (int r = 0; r < 4; r++) { mrow[r] = -1e30f; lrow[r] = 0.f; }

        const int ntile = qt + 1;
        for (int ti = 0; ti < ntile; ti++) {
            const int s0 = ti << 6;
            // prefetch: next tile, or tile 0 for phase 1's start (ph0 tail)
            const int nxt = (ti + 1 < ntile) ? (s0 + 64) : (ph == 0 ? 0 : -1);
            if (nxt >= 0) LOADKV(nxt);
            // QK^T: S (16q x 64s) per wave (scale pre-folded into Q)
            f32x4 sacc[4] = {};
            __builtin_amdgcn_s_setprio(1);
#pragma unroll
            for (int ch = 0; ch < 4; ch++) {
#pragma unroll
                for (int ni = 0; ni < 4; ni++) {
                    int row = ni * 16 + fr;
                    s16x8 kf = *(const s16x8*)((char*)Ks + row * 256 +
                                               ((ch * 64 + kg * 16) ^ ((row & 7) << 4)));
                    sacc[ni] = __builtin_amdgcn_mfma_f32_16x16x32_bf16(qa[ch], kf, sacc[ni], 0, 0, 0);
                }
            }
            __builtin_amdgcn_s_setprio(0);
            // causal mask + per-row tile max
            const bool diag = (s0 == q0);
            float sv[4][4];
            float tm[4] = {-1e30f, -1e30f, -1e30f, -1e30f};
#pragma unroll
            for (int ni = 0; ni < 4; ni++)
#pragma unroll
                for (int r = 0; r < 4; r++) {
                    float x = sacc[ni][r];
                    if (diag && (ni * 16 + fr > wid * 16 + kg * 4 + r)) x = -1e30f;
                    sv[ni][r] = x;
                    tm[r] = fmaxf(tm[r], x);
                }
#pragma unroll
            for (int r = 0; r < 4; r++)
#pragma unroll
                for (int off = 1; off < 16; off <<= 1)
                    tm[r] = fmaxf(tm[r], __shfl_xor(tm[r], off));
            // defer-max (T13)
            int ok = 1;
#pragma unroll
            for (int r = 0; r < 4; r++) ok &= (tm[r] <= mrow[r] + 8.0f);
            if (!__all(ok)) {
#pragma unroll
                for (int r = 0; r < 4; r++) {
                    float mnew = fmaxf(mrow[r], tm[r]);
                    float sc = __expf(mrow[r] - mnew);
                    mrow[r] = mnew;
                    lrow[r] *= sc;
#pragma unroll
                    for (int di = 0; di < 8; di++) oacc[di][r] *= sc;
                }
            }
            // P = exp(S - m); per-lane partial row-sums
#pragma unroll
            for (int ni = 0; ni < 4; ni++)
#pragma unroll
                for (int r = 0; r < 4; r++) {
                    float p = __expf(sv[ni][r] - mrow[r]);
                    sv[ni][r] = p;
                    lrow[r] += p;
                }
            // write P to per-wave LDS; swizzle carries kg bit1 too (bank-complete)
#pragma unroll
            for (int ni = 0; ni < 4; ni++)
#pragma unroll
                for (int r = 0; r < 4; r++) {
                    int row = kg * 4 + r;
                    int cb = (ni * 16 + fr) * 2;
                    *(short*)((char*)Ps + wid * 2048 + row * 128 +
                              (cb ^ ((row & 7) << 4) ^ ((row & 8) << 2))) = f2b(sv[ni][r]);
                }
            // PV: O (16q x 128d) += P (16x64) * V (64x128)
            s16x8 pa[2];
#pragma unroll
            for (int sc2 = 0; sc2 < 2; sc2++)
                pa[sc2] = *(const s16x8*)((char*)Ps + wid * 2048 + fr * 128 +
                                          ((sc2 * 64 + kg * 16) ^ ((fr & 7) << 4) ^ ((fr & 8) << 2)));
            __builtin_amdgcn_s_setprio(1);
#pragma unroll
            for (int di = 0; di < 8; di++) {
                int row = di * 16 + fr;
#pragma unroll
                for (int sc2 = 0; sc2 < 2; sc2++) {
                    s16x8 vf = *(const s16x8*)((char*)Vs + row * 128 +
                                               ((sc2 * 64 + kg * 16) ^ ((row & 7) << 4)));
                    oacc[di] = __builtin_amdgcn_mfma_f32_16x16x32_bf16(pa[sc2], vf, oacc[di], 0, 0, 0);
                }
            }
            __builtin_amdgcn_s_setprio(0);
            __syncthreads();              // all waves done reading tile ti
            if (nxt >= 0) WRITEKV();      // cheap reg->LDS; loads already landed
            __syncthreads();
        }
        // deferred l reduce + epilogue for this q-tile
#pragma unroll
        for (int r = 0; r < 4; r++)
#pragma unroll
            for (int off = 1; off < 16; off <<= 1)
                lrow[r] += __shfl_xor(lrow[r], off);
#pragma unroll
        for (int r = 0; r < 4; r++) {
            float rl = 1.f / lrow[r];
            int qg = q0 + wid * 16 + kg * 4 + r;
            size_t orow = (size_t)(b * L_ + qg) * E_ + h * D_;
#pragma unroll
            for (int di = 0; di < 8; di++)
                O[orow + di * 16 + fr] = f2b(oacc[di][r] * rl);
        }
    }
#undef LOADKV
#undef WRITEKV
}

extern "C" void kernel_launch(void* const* d_in, const int* in_sizes, int n_in,
                              void* d_out, int out_size, void* d_ws, size_t ws_size,
                              hipStream_t stream) {
    const float* x     = (const float*)d_in[0];
    const float* wqkv  = (const float*)d_in[1];
    const float* bqkv  = (const float*)d_in[2];
    const float* wout  = (const float*)d_in[3];
    const float* bout  = (const float*)d_in[4];
    float* out = (float*)d_out;
    char* ws = (char*)d_ws;

    const size_t SZ_XB    = (size_t)4096 * 2048 * 2;
    const size_t SZ_WQKV  = (size_t)6144 * 2048 * 2;
    const size_t SZ_WOUT  = (size_t)2048 * 2048 * 2;
    const size_t SZ_QKV   = (size_t)4096 * 6144 * 2;
    const size_t SZ_HLD   = (size_t)32 * 2048 * 128 * 2;
    short* xb    = (short*)(ws);
    short* wqkvb = (short*)(ws + SZ_XB);
    short* woutb = (short*)(ws + SZ_XB + SZ_WQKV);
    short* qkvb  = (short*)(ws + SZ_XB + SZ_WQKV + SZ_WOUT);
    short* qb    = (short*)(ws + SZ_XB + SZ_WQKV + SZ_WOUT + SZ_QKV);
    short* kb    = (short*)(ws + SZ_XB + SZ_WQKV + SZ_WOUT + SZ_QKV + SZ_HLD);
    short* vtb   = (short*)(ws + SZ_XB + SZ_WQKV + SZ_WOUT + SZ_QKV + 2 * SZ_HLD);
    float2* trig = (float2*)(ws + SZ_XB + SZ_WQKV + SZ_WOUT + SZ_QKV + 3 * SZ_HLD);
    short* ob    = xb;  // alias: xb dead after GEMM1
    const size_t NEEDED = SZ_XB + SZ_WQKV + SZ_WOUT + SZ_QKV + 3 * SZ_HLD + (size_t)L_ * 64 * 8;
    if (ws_size < NEEDED) return;

    cvt_kernel<<<8192, 256, 0, stream>>>(x, xb, 2097152);
    cvt_kernel<<<12288, 256, 0, stream>>>(wqkv, wqkvb, 3145728);
    cvt_kernel<<<4096, 256, 0, stream>>>(wout, woutb, 1048576);
    trig_kernel<<<512, 256, 0, stream>>>(trig);

    gemm_bt<1><<<dim3(32, 48), 256, 0, stream>>>(xb, wqkvb, bqkv, (void*)qkvb, 4096, 6144, 2048);
    rearrange_rope<<<1024, 256, 0, stream>>>(qkvb, trig, qb, kb, vtb);
    attn_kernel<<<512, 256, 0, stream>>>(qb, kb, vtb, ob);
    gemm_bt<0><<<dim3(32, 16), 256, 0, stream>>>(ob, woutb, bout, (void*)out, 4096, 2048, 2048);
}